// Round 5
// baseline (219.964 us; speedup 1.0000x reference)
//
#include <hip/hip_runtime.h>
#include <math.h>

#define SRC 448
#define OUTN 224
#define PAIRS_PER_ROW 112            // 224/2 pixel-pairs per output row
#define PAIRS_PER_IMG (OUTN * PAIRS_PER_ROW)   // 25088
#define BPI (PAIRS_PER_IMG / 256)    // 98 blocks per image

__device__ __forceinline__ float sig10(float z) {
    return 1.0f / (1.0f + __expf(-10.0f * z));
}

__global__ __launch_bounds__(256) void attn_crop_kernel(
    const float* __restrict__ img,   // [B,3,448,448]
    const float* __restrict__ locs,  // [B,3]
    float* __restrict__ out)         // [B,3,224,224]
{
    const int b = blockIdx.y;
    const int pair = blockIdx.x * 256 + threadIdx.x;   // < 25088 always
    const int jr = pair / PAIRS_PER_ROW;
    const int jc0 = (pair - jr * PAIRS_PER_ROW) * 2;   // even column

    const float Sf = (float)SRC;
    float tx = locs[b * 3 + 0];
    float ty = locs[b * 3 + 1];
    float tl = locs[b * 3 + 2];
    // exact reference clamp order (jnp.clip = min(max(x,lo),hi))
    tl = fminf(fmaxf(tl, Sf / 3.0f), Sf * 2.0f / 3.0f);
    tx = fminf(fmaxf(tx, tl), Sf - tl);
    ty = fminf(fmaxf(ty, tl), Sf - tl);
    const float w_off = fmaxf(floorf(tx - tl), 0.0f);
    const float h_off = fmaxf(floorf(ty - tl), 0.0f);
    const float w_end = fminf(floorf(tx + tl), Sf);
    const float h_end = fminf(floorf(ty + tl), Sf);
    const float Lw = w_end - w_off;
    const float Lh = h_end - h_off;

    const float inv = 1.0f / (float)(OUTN - 1);

    // ---- row (shared by both pixels) ----
    const float r = w_off + ((float)jr * inv) * (Lw - 1.0f);
    const float r0 = fminf(fmaxf(floorf(r), 0.0f), Sf - 1.0f);
    const float wr = r - r0;
    const int r0i = (int)r0;
    const int r1i = min(r0i + 1, SRC - 1);
    const float mx0 = sig10((float)r0i - w_off) - sig10((float)r0i - w_end);
    const float mx1 = sig10((float)r1i - w_off) - sig10((float)r1i - w_end);

    // ---- cols (two adjacent output pixels) ----
    float wcA, wcB;
    int c0A, c1A, c0B, c1B;
    float myA0, myA1, myB0, myB1;
    {
        const float c = h_off + ((float)jc0 * inv) * (Lh - 1.0f);
        const float c0 = fminf(fmaxf(floorf(c), 0.0f), Sf - 1.0f);
        wcA = c - c0;
        c0A = (int)c0;
        c1A = min(c0A + 1, SRC - 1);
        myA0 = sig10((float)c0A - h_off) - sig10((float)c0A - h_end);
        myA1 = sig10((float)c1A - h_off) - sig10((float)c1A - h_end);
    }
    {
        const float c = h_off + ((float)(jc0 + 1) * inv) * (Lh - 1.0f);
        const float c0 = fminf(fmaxf(floorf(c), 0.0f), Sf - 1.0f);
        wcB = c - c0;
        c0B = (int)c0;
        c1B = min(c0B + 1, SRC - 1);
        myB0 = sig10((float)c0B - h_off) - sig10((float)c0B - h_end);
        myB1 = sig10((float)c1B - h_off) - sig10((float)c1B - h_end);
    }

    const float a00 = (1.0f - wr) * (1.0f - wcA) * mx0 * myA0;
    const float a01 = (1.0f - wr) * wcA          * mx0 * myA1;
    const float a10 = wr          * (1.0f - wcA) * mx1 * myA0;
    const float a11 = wr          * wcA          * mx1 * myA1;
    const float b00 = (1.0f - wr) * (1.0f - wcB) * mx0 * myB0;
    const float b01 = (1.0f - wr) * wcB          * mx0 * myB1;
    const float b10 = wr          * (1.0f - wcB) * mx1 * myB0;
    const float b11 = wr          * wcB          * mx1 * myB1;

    const float* base = img + (size_t)b * 3 * SRC * SRC;
    float* ob = out + (size_t)b * 3 * OUTN * OUTN + (size_t)jr * OUTN + jc0;

#pragma unroll
    for (int ch = 0; ch < 3; ++ch) {
        const float* pr0 = base + (size_t)ch * SRC * SRC + (size_t)r0i * SRC;
        const float* pr1 = base + (size_t)ch * SRC * SRC + (size_t)r1i * SRC;
        const float vA00 = pr0[c0A], vA01 = pr0[c1A];
        const float vA10 = pr1[c0A], vA11 = pr1[c1A];
        const float vB00 = pr0[c0B], vB01 = pr0[c1B];
        const float vB10 = pr1[c0B], vB11 = pr1[c1B];
        float2 res;
        res.x = vA00 * a00 + vA01 * a01 + vA10 * a10 + vA11 * a11;
        res.y = vB00 * b00 + vB01 * b01 + vB10 * b10 + vB11 * b11;
        *reinterpret_cast<float2*>(ob + (size_t)ch * OUTN * OUTN) = res;  // 8B aligned (jc0 even)
    }
}

extern "C" void kernel_launch(void* const* d_in, const int* in_sizes, int n_in,
                              void* d_out, int out_size, void* d_ws, size_t ws_size,
                              hipStream_t stream) {
    const float* img  = (const float*)d_in[0];
    const float* locs = (const float*)d_in[1];
    float* out = (float*)d_out;

    const int B = in_sizes[1] / 3;  // 64
    dim3 block(256);
    dim3 grid(BPI, B);   // 98 x 64
    attn_crop_kernel<<<grid, block, 0, stream>>>(img, locs, out);
}

// Round 6
// 215.753 us; speedup vs baseline: 1.0195x; 1.0195x over previous
//
#include <hip/hip_runtime.h>
#include <math.h>

#define SRC 448
#define OUTN 224

__device__ __forceinline__ float sig10(float z) {
    // sigmoid(10*z); IEEE inf handling gives exact 0/1 saturation
    return 1.0f / (1.0f + __expf(-10.0f * z));
}

__global__ __launch_bounds__(256) void attn_crop_kernel(
    const float* __restrict__ img,   // [B,3,448,448]
    const float* __restrict__ locs,  // [B,3]
    float* __restrict__ out)         // [B,3,224,224]
{
    const int b = blockIdx.y;
    const int pix = blockIdx.x * 256 + threadIdx.x;
    if (pix >= OUTN * OUTN) return;
    const int jr = pix / OUTN;
    const int jc = pix - jr * OUTN;

    const float Sf = (float)SRC;
    float tx = locs[b * 3 + 0];
    float ty = locs[b * 3 + 1];
    float tl = locs[b * 3 + 2];
    // exact reference clamp order (jnp.clip = min(max(x,lo),hi))
    tl = fminf(fmaxf(tl, Sf / 3.0f), Sf * 2.0f / 3.0f);
    tx = fminf(fmaxf(tx, tl), Sf - tl);
    ty = fminf(fmaxf(ty, tl), Sf - tl);
    const float w_off = fmaxf(floorf(tx - tl), 0.0f);
    const float h_off = fmaxf(floorf(ty - tl), 0.0f);
    const float w_end = fminf(floorf(tx + tl), Sf);
    const float h_end = fminf(floorf(ty + tl), Sf);
    const float Lw = w_end - w_off;
    const float Lh = h_end - h_off;

    const float inv = 1.0f / (float)(OUTN - 1);
    const float r = w_off + ((float)jr * inv) * (Lw - 1.0f);
    const float c = h_off + ((float)jc * inv) * (Lh - 1.0f);
    const float r0 = fminf(fmaxf(floorf(r), 0.0f), Sf - 1.0f);
    const float c0 = fminf(fmaxf(floorf(c), 0.0f), Sf - 1.0f);
    const float wr = r - r0;
    const float wc = c - c0;
    const int r0i = (int)r0;
    const int c0i = (int)c0;
    const int r1i = min(r0i + 1, SRC - 1);
    const int c1i = min(c0i + 1, SRC - 1);

    // soft-mask values at the 4 tap rows/cols (folded into weights)
    const float mx0 = sig10((float)r0i - w_off) - sig10((float)r0i - w_end);
    const float mx1 = sig10((float)r1i - w_off) - sig10((float)r1i - w_end);
    const float my0 = sig10((float)c0i - h_off) - sig10((float)c0i - h_end);
    const float my1 = sig10((float)c1i - h_off) - sig10((float)c1i - h_end);

    const float w00 = (1.0f - wr) * (1.0f - wc) * mx0 * my0;
    const float w01 = (1.0f - wr) * wc          * mx0 * my1;
    const float w10 = wr          * (1.0f - wc) * mx1 * my0;
    const float w11 = wr          * wc          * mx1 * my1;

    const float* base = img + (size_t)b * 3 * SRC * SRC;
    float* ob = out + (size_t)b * 3 * OUTN * OUTN + (size_t)jr * OUTN + jc;

#pragma unroll
    for (int ch = 0; ch < 3; ++ch) {
        const float* p = base + (size_t)ch * SRC * SRC;
        const float v00 = p[r0i * SRC + c0i];
        const float v01 = p[r0i * SRC + c1i];
        const float v10 = p[r1i * SRC + c0i];
        const float v11 = p[r1i * SRC + c1i];
        ob[(size_t)ch * OUTN * OUTN] = v00 * w00 + v01 * w01 + v10 * w10 + v11 * w11;
    }
}

extern "C" void kernel_launch(void* const* d_in, const int* in_sizes, int n_in,
                              void* d_out, int out_size, void* d_ws, size_t ws_size,
                              hipStream_t stream) {
    const float* img  = (const float*)d_in[0];
    const float* locs = (const float*)d_in[1];
    float* out = (float*)d_out;

    const int B = in_sizes[1] / 3;  // 64
    dim3 block(256);
    dim3 grid((OUTN * OUTN + 255) / 256, B);
    attn_crop_kernel<<<grid, block, 0, stream>>>(img, locs, out);
}